// Round 18
// baseline (328.241 us; speedup 1.0000x reference)
//
#include <hip/hip_runtime.h>
#include <stdint.h>

typedef unsigned short u16;
typedef unsigned int u32;
typedef __attribute__((ext_vector_type(4))) float f32x4;
typedef __attribute__((ext_vector_type(8))) __bf16 bf16x8;

#define EPS_BN 1e-5f

__device__ __forceinline__ u16 f2bf(float f) {
  u32 u = __builtin_bit_cast(u32, f);
  u32 r = (u + 0x7fffu + ((u >> 16) & 1u)) >> 16;
  return (u16)r;
}

__device__ __forceinline__ float silu_f(float v) {
  return v / (1.0f + __expf(-v));
}

// async global->LDS, 16B per lane; dest = wave-uniform base + lane*16
__device__ __forceinline__ void gll16(const void* g, void* l) {
  __builtin_amdgcn_global_load_lds(
      (__attribute__((address_space(1))) void*)(void*)g,
      (__attribute__((address_space(3))) void*)l, 16, 0, 0);
}

// ---------------------------------------------------------------------------
// FUSED prep + NCHW->NHWC transpose (r17-proven). 5120 blocks; every block
// does one (b,h,ctile) transpose tile; the first 2304 blocks also run prep's
// weight-pack/BN-fold lines (disjoint outputs -> race-free).
// ---------------------------------------------------------------------------
__global__ __launch_bounds__(256) void prep_nchw(
    const float* __restrict__ x,
    const float* __restrict__ qkv_w, const float* __restrict__ qg,
    const float* __restrict__ qb, const float* __restrict__ qm,
    const float* __restrict__ qv,
    const float* __restrict__ hid_w, const float* __restrict__ hg,
    const float* __restrict__ hb, const float* __restrict__ hm,
    const float* __restrict__ hv,
    const float* __restrict__ out_w, const float* __restrict__ og,
    const float* __restrict__ ob, const float* __restrict__ om,
    const float* __restrict__ ov,
    u16* __restrict__ xn,
    u16* __restrict__ wtb, u16* __restrict__ w2b, u16* __restrict__ wqp,
    float* __restrict__ bnq_s, float* __restrict__ bnq_b,
    float* __restrict__ bnh_s, float* __restrict__ bnh_b,
    float* __restrict__ bn2s, float* __restrict__ bn2b,
    float* __restrict__ zpg)
{
  __shared__ u16 T[80 * 66];
  const int t = threadIdx.x;
  const int ct = blockIdx.x;       // 0..3
  const int h  = blockIdx.y;       // 0..79
  const int b  = blockIdx.z;       // 0..15
  const int bid = blockIdx.x + blockIdx.y * 4 + blockIdx.z * 320;  // 0..5119
  const int gid = bid * 256 + t;

  // ---- prep lines (first 2304 blocks only) ----
  if (gid < 256 * 2304) {            // hid weights, channel-major
    int j = gid / 2304, k = gid - j * 2304;
    int tap = k >> 8, c = k & 255;
    wtb[gid] = f2bf(hid_w[(j * 256 + c) * 9 + tap]);
  }
  if (gid < 73728) {                 // qkv grouped weights [g][j<32][288]
    int g = gid / 9216;
    int r = gid - g * 9216;
    int j = r / 288, k = r - j * 288;
    int tap = k >> 5, cg = k & 31;
    float v = 0.f;
    if (j < 20) v = qkv_w[((g * 20 + j) * 32 + cg) * 9 + tap];
    wqp[gid] = f2bf(v);
  }
  if (gid < 98304) w2b[gid] = f2bf(out_w[gid]);   // [256][384]
  if (gid < 160) {
    float iv = qg[gid] * rsqrtf(qv[gid] + EPS_BN);
    bnq_s[gid] = iv; bnq_b[gid] = qb[gid] - qm[gid] * iv;
  }
  if (gid < 256) {
    float iv = hg[gid] * rsqrtf(hv[gid] + EPS_BN);
    bnh_s[gid] = iv; bnh_b[gid] = hb[gid] - hm[gid] * iv;
    float iv2 = og[gid] * rsqrtf(ov[gid] + EPS_BN);
    bn2s[gid] = iv2; bn2b[gid] = ob[gid] - om[gid] * iv2;
  }
  if (gid < 64) zpg[gid] = 0.f;

  // ---- transpose tile (all blocks) ----
  const float* src = x + ((size_t)b * 256 + ct * 64) * 6400 + h * 80;
  for (int it = 0; it < 5; ++it) {
    int idx = it * 256 + t;        // 0..1279 float4s
    int cl = idx / 20, w4 = idx - cl * 20;
    float4 v = *(const float4*)(src + (size_t)cl * 6400 + w4 * 4);
    T[(w4 * 4 + 0) * 66 + cl] = f2bf(v.x);
    T[(w4 * 4 + 1) * 66 + cl] = f2bf(v.y);
    T[(w4 * 4 + 2) * 66 + cl] = f2bf(v.z);
    T[(w4 * 4 + 3) * 66 + cl] = f2bf(v.w);
  }
  __syncthreads();
  u16* dst = xn + ((size_t)(b * 80 + h) * 80) * 256 + ct * 64;
  for (int it = 0; it < 5; ++it) {
    int idx = it * 256 + t;
    int wl = idx >> 4;
    int cl = (idx & 15) * 4;
    ushort4 v4;
    v4.x = T[wl * 66 + cl + 0];
    v4.y = T[wl * 66 + cl + 1];
    v4.z = T[wl * 66 + cl + 2];
    v4.w = T[wl * 66 + cl + 3];
    *(ushort4*)(dst + (size_t)wl * 256 + cl) = v4;
  }
}

// ---------------------------------------------------------------------------
// hid GEMM (r13-proven, 146us): 128px x 256ch per block, 8 waves
// (wave = 64px x 64col strip), 2-barrier K-step, XOR swizzle, A staged once
// per step in the 36-step interleaved order (cross-block L2 locality).
// ---------------------------------------------------------------------------
__global__ __launch_bounds__(512, 4) void gemm_main(
    const u16* __restrict__ xn, const u16* __restrict__ wt,
    const float* __restrict__ bns, const float* __restrict__ bnb,
    const float* __restrict__ zpg, u16* __restrict__ ycat)
{
  __shared__ __attribute__((aligned(16))) u16 Al[128 * 64];  // 16 KB
  __shared__ __attribute__((aligned(16))) u16 Bl[256 * 64];  // 32 KB
  const int t = threadIdx.x;
  const int wave = t >> 6, lane = t & 63;
  const int wm = wave >> 2;            // 0..1 : 64-px strip
  const int wn = wave & 3;             // 0..3 : 64-col strip
  // bijective XCD swizzle: nwg = 800 = 8*100
  const int orig = blockIdx.x;
  const int wg = (orig & 7) * 100 + (orig >> 3);
  const int ptile = wg * 128;

  const int srcc = (((lane & 7) ^ ((lane >> 3) & 7)) * 8);
  const int c16 = lane & 15, lq = lane >> 4;

  int pbA[2], hhA[2], wwA[2];
#pragma unroll
  for (int l = 0; l < 2; ++l) {
    int row = wave * 8 + (lane >> 3) + l * 64;
    int p = ptile + row;
    pbA[l] = p;
    int hw = p % 6400;
    hhA[l] = hw / 80;
    wwA[l] = hw - (hw / 80) * 80;
  }
  int bofB[4];
#pragma unroll
  for (int l = 0; l < 4; ++l) {
    int row = wave * 8 + (lane >> 3) + l * 64;
    bofB[l] = row * 2304 + srcc;
  }

  f32x4 acc[4][4];
#pragma unroll
  for (int m = 0; m < 4; ++m)
#pragma unroll
    for (int n = 0; n < 4; ++n) {
      f32x4 z = {0.f, 0.f, 0.f, 0.f};
      acc[m][n] = z;
    }

  for (int ks = 0; ks < 36; ++ks) {
    const int k0 = ks * 64;
    const int tap = ks >> 2;
    const int c0 = (ks & 3) * 64;
    const int dh = tap / 3 - 1, dw = tap - (tap / 3) * 3 - 1;
    const int dp = dh * 80 + dw;
    __syncthreads();
#pragma unroll
    for (int l = 0; l < 2; ++l) {
      bool ok = ((unsigned)(hhA[l] + dh) < 80u) & ((unsigned)(wwA[l] + dw) < 80u);
      const u16* src = ok
          ? (xn + ((size_t)(pbA[l] + dp) * 256 + c0 + srcc))
          : (const u16*)zpg;
      gll16(src, Al + (wave * 8 + l * 64) * 64);
    }
#pragma unroll
    for (int l = 0; l < 4; ++l)
      gll16(wt + (size_t)(bofB[l] + k0), Bl + (wave * 8 + l * 64) * 64);
    __syncthreads();
#pragma unroll
    for (int kk = 0; kk < 2; ++kk) {
      const int q = kk * 4 + lq;
      bf16x8 av[4], bv[4];
#pragma unroll
      for (int m = 0; m < 4; ++m) {
        int r = wm * 64 + m * 16 + c16;           // 0..127
        av[m] = *(const bf16x8*)(Al + r * 64 + (q ^ (r & 7)) * 8);
      }
#pragma unroll
      for (int n = 0; n < 4; ++n) {
        int j = wn * 64 + n * 16 + c16;           // 0..255
        bv[n] = *(const bf16x8*)(Bl + j * 64 + (q ^ (j & 7)) * 8);
      }
#pragma unroll
      for (int m = 0; m < 4; ++m)
#pragma unroll
        for (int n = 0; n < 4; ++n)
          acc[m][n] = __builtin_amdgcn_mfma_f32_16x16x32_bf16(
              av[m], bv[n], acc[m][n], 0, 0, 0);
    }
  }

  const int rg = lq;
#pragma unroll
  for (int n = 0; n < 4; ++n) {
    int j = wn * 64 + n * 16 + c16;               // 0..255
    float sc = bns[j], bi = bnb[j];
#pragma unroll
    for (int m = 0; m < 4; ++m) {
      int p0 = ptile + wm * 64 + m * 16 + rg * 4;
#pragma unroll
      for (int r = 0; r < 4; ++r) {
        float v = silu_f(acc[m][n][r] * sc + bi);
        ycat[(size_t)(p0 + r) * 384 + 128 + j] = f2bf(v);
      }
    }
  }
}

// ---------------------------------------------------------------------------
// FUSED qkv grouped conv + per-pixel attention, HALO-STAGED, 8-WAVE variant:
// same r12-proven buffers/barriers/swizzle, but 512 threads (wave owns 16
// pixels, acc[16] = 64 VGPR) -> 2 blocks/CU = 16 waves/CU (2x TLP to hide
// the stage drains). STAGE(cc+1) still issued before the 9-tap compute.
// Epilogue: qs[128][160] fp32 overlay -> softmax + PV -> Ycat cols 0..127.
// ---------------------------------------------------------------------------
__global__ __launch_bounds__(512, 4) void qkv_attn(
    const u16* __restrict__ xn, const u16* __restrict__ wqp,
    const float* __restrict__ bnq_s, const float* __restrict__ bnq_b,
    u16* __restrict__ ycat)
{
  __shared__ __attribute__((aligned(16))) char LB[81920];
  u16* HB0 = (u16*)LB;                 // halo buf 0: [320*64]
  u16* HB1 = (u16*)(LB + 40960);       // halo buf 1
  float* qs = (float*)LB;              // overlay: [128][160] fp32

  const int t = threadIdx.x;
  const int wave = t >> 6, lane = t & 63;   // wave 0..7
  // bijective XCD swizzle: nwg = 800 = 8*100
  const int orig = blockIdx.x;
  const int wg = (orig & 7) * 100 + (orig >> 3);
  const int ptile = wg * 128;
  const int pbase = ptile - 88;        // multiple of 8 -> swizzle rows align

  const int srcc = (((lane & 7) ^ ((lane >> 3) & 7)) * 8);
  const int q = lane >> 4, c16 = lane & 15;

  // per-lane pixel coords for its single fragment row
  const int p_ = ptile + wave * 16 + c16;
  const int hw_ = p_ % 6400;
  const int ph = hw_ / 80;
  const int pw = hw_ - (hw_ / 80) * 80;

  // stage halo window for channel chunk cc into dst (5 gll16 per wave)
  auto STAGE_H = [&](int cc, u16* dst) {
#pragma unroll
    for (int r = 0; r < 5; ++r) {
      int row = r * 64 + wave * 8 + (lane >> 3);
      int p = pbase + row;
      int pc = p < 0 ? 0 : (p > 102399 ? 102399 : p);
      gll16(xn + (size_t)pc * 256 + cc * 64 + srcc,
            dst + (r * 64 + wave * 8) * 64);
    }
  };

  bf16x8 zv;
#pragma unroll
  for (int i = 0; i < 8; ++i) zv[i] = (__bf16)0.0f;

  f32x4 acc[16];
#pragma unroll
  for (int f = 0; f < 16; ++f) {
    f32x4 z = {0.f, 0.f, 0.f, 0.f};
    acc[f] = z;
  }

  STAGE_H(0, HB0);
  asm volatile("s_waitcnt vmcnt(0)" ::: "memory");
  __builtin_amdgcn_sched_barrier(0);
  __syncthreads();

#pragma unroll
  for (int cc = 0; cc < 4; ++cc) {
    const u16* HBc = (cc & 1) ? HB1 : HB0;
    u16* HBn = (cc & 1) ? HB0 : HB1;
    if (cc < 3) STAGE_H(cc + 1, HBn);   // in flight across the whole compute
    for (int tap = 0; tap < 9; ++tap) {
      const int dh = tap / 3 - 1, dw = tap - (tap / 3) * 3 - 1;
      const int dp = dh * 80 + dw;
      bf16x8 bq[2][2];
#pragma unroll
      for (int h = 0; h < 2; ++h)
#pragma unroll
        for (int nf = 0; nf < 2; ++nf) {
          int row = (2 * cc + h) * 32 + nf * 16 + c16;
          bq[h][nf] =
              *(const bf16x8*)(wqp + (size_t)row * 288 + tap * 32 + q * 8);
        }
      const int rl = wave * 16 + c16 + 88 + dp;      // halo row
      const bool ok = ((unsigned)(ph + dh) < 80u) &
                      ((unsigned)(pw + dw) < 80u);
      bf16x8 av[2];
#pragma unroll
      for (int h = 0; h < 2; ++h) {
        int q8 = h * 4 + q;
        bf16x8 raw = *(const bf16x8*)(HBc + rl * 64 + ((q8 ^ (rl & 7)) * 8));
        av[h] = ok ? raw : zv;
      }
#pragma unroll
      for (int h = 0; h < 2; ++h)
#pragma unroll
        for (int nf = 0; nf < 2; ++nf)
          acc[(2 * cc + h) * 2 + nf] = __builtin_amdgcn_mfma_f32_16x16x32_bf16(
              av[h], bq[h][nf], acc[(2 * cc + h) * 2 + nf], 0, 0, 0);
    }
    if (cc < 3) {
      asm volatile("s_waitcnt vmcnt(0)" ::: "memory");  // pre-drained by compute
      __builtin_amdgcn_sched_barrier(0);
      __syncthreads();
    }
  }

  // fence all waves before the qs overlay is written over the halo buffers
  asm volatile("s_waitcnt vmcnt(0)" ::: "memory");
  __builtin_amdgcn_sched_barrier(0);
  __syncthreads();

  // epilogue: BN+SiLU -> qs[pixel][oc] fp32 (pixel 0..127, oc 0..159)
#pragma unroll
  for (int f = 0; f < 16; ++f) {
    int jj = (f & 1) * 16 + c16;
    if (jj >= 20) continue;
    int oc = (f >> 1) * 20 + jj;
    float sc = bnq_s[oc], bi = bnq_b[oc];
    int pl0 = wave * 16 + q * 4;
#pragma unroll
    for (int r = 0; r < 4; ++r)
      qs[(pl0 + r) * 160 + oc] = silu_f(acc[f][r] * sc + bi);
  }
  __syncthreads();

  // attention: thread -> (px, i); 4 iters cover 128 px * 16 i (512 thr).
  for (int it = 0; it < 4; ++it) {
    int idx = it * 512 + t;
    int px = idx >> 4, i = idx & 15;
    const float* row = qs + px * 160;
    const float qi = row[i];
    float s[16];
    float mx = -3.4e38f;
#pragma unroll
    for (int j = 0; j < 16; ++j) { s[j] = qi * row[16 + j]; mx = fmaxf(mx, s[j]); }
    float sum = 0.f;
#pragma unroll
    for (int j = 0; j < 16; ++j) { s[j] = __expf(s[j] - mx); sum += s[j]; }
    const float inv = 1.0f / sum;
    float y[8];
#pragma unroll
    for (int d = 0; d < 8; ++d) y[d] = 0.f;
#pragma unroll
    for (int j = 0; j < 16; ++j) {
      const float a = s[j];
      const float* vr = row + 32 + j * 8;
#pragma unroll
      for (int d = 0; d < 8; ++d) y[d] += a * vr[d];
    }
    union { u16 u[8]; uint4 v4; } pk;
#pragma unroll
    for (int d = 0; d < 8; ++d) pk.u[d] = f2bf(y[d] * inv);
    *(uint4*)(ycat + (size_t)(ptile + px) * 384 + i * 8) = pk.v4;
  }
}

// ---------------------------------------------------------------------------
// Output GEMM (r12-proven form, ~45us = near its HBM/L3 roofline):
// 128oc x 128px per block, 256 threads, 2-barrier K-step, XOR swizzle,
// XCD swizzle over 1600 wgs. Coalesced NCHW fp32 stores.
// ---------------------------------------------------------------------------
__global__ __launch_bounds__(256, 2) void gemm_out(
    const u16* __restrict__ w2, const u16* __restrict__ ycat,
    const float* __restrict__ bns, const float* __restrict__ bnb,
    float* __restrict__ out)
{
  __shared__ __attribute__((aligned(16))) u16 Al[128 * 64];
  __shared__ __attribute__((aligned(16))) u16 Bl[128 * 64];
  const int t = threadIdx.x;
  const int wave = t >> 6, lane = t & 63;
  const int wr = wave >> 1, wc = wave & 1;
  const int orig = blockIdx.y * 2 + blockIdx.x;
  const int wg = (orig & 7) * 200 + (orig >> 3);
  const int octile = (wg / 800) * 128;
  const int ptile = (wg % 800) * 128;

  const int srcc = (((lane & 7) ^ ((lane >> 3) & 7)) * 8);
  int bofA[4], bofB[4];
#pragma unroll
  for (int c = 0; c < 4; ++c) {
    int m = wave * 32 + c * 8 + (lane >> 3);
    bofA[c] = (octile + m) * 384 + srcc;
    bofB[c] = (ptile + m) * 384 + srcc;
  }
  u16* AlW = Al + wave * 2048;
  u16* BlW = Bl + wave * 2048;

  f32x4 acc[4][4];
#pragma unroll
  for (int m = 0; m < 4; ++m)
#pragma unroll
    for (int n = 0; n < 4; ++n) {
      f32x4 z = {0.f, 0.f, 0.f, 0.f};
      acc[m][n] = z;
    }

  for (int ks = 0; ks < 6; ++ks) {
    const int k0 = ks * 64;
    __syncthreads();
#pragma unroll
    for (int c = 0; c < 4; ++c) gll16(w2 + (size_t)(bofA[c] + k0), AlW + c * 512);
#pragma unroll
    for (int c = 0; c < 4; ++c) gll16(ycat + (size_t)(bofB[c] + k0), BlW + c * 512);
    __syncthreads();
#pragma unroll
    for (int kk = 0; kk < 2; ++kk) {
      const int q = kk * 4 + (lane >> 4);
      const int c16 = lane & 15;
      bf16x8 av[4], bv[4];
#pragma unroll
      for (int m = 0; m < 4; ++m) {
        int r = wr * 64 + m * 16 + c16;
        av[m] = *(const bf16x8*)(Al + r * 64 + (q ^ (r & 7)) * 8);
      }
#pragma unroll
      for (int n = 0; n < 4; ++n) {
        int r = wc * 64 + n * 16 + c16;
        bv[n] = *(const bf16x8*)(Bl + r * 64 + (q ^ (r & 7)) * 8);
      }
#pragma unroll
      for (int m = 0; m < 4; ++m)
#pragma unroll
        for (int n = 0; n < 4; ++n)
          acc[m][n] = __builtin_amdgcn_mfma_f32_16x16x32_bf16(
              av[m], bv[n], acc[m][n], 0, 0, 0);
    }
  }

  const int c16 = lane & 15, rg = lane >> 4;
  const int b = ptile / 6400;
  const int hwb = ptile - b * 6400;
#pragma unroll
  for (int m = 0; m < 4; ++m) {
    int oc0 = octile + wr * 64 + m * 16 + rg * 4;
#pragma unroll
    for (int n = 0; n < 4; ++n) {
      int hw = hwb + wc * 64 + n * 16 + c16;
#pragma unroll
      for (int r = 0; r < 4; ++r) {
        int oc = oc0 + r;
        float v = silu_f(acc[m][n][r] * bns[oc] + bnb[oc]);
        out[((size_t)b * 256 + oc) * 6400 + hw] = v;
      }
    }
  }
}

// ---------------------------------------------------------------------------
// ws layout (bytes):
//   0        zero page (256)
//   256      bnq_s(640) 1280 bnq_b(640) 2304 bnh_s(1024) 3328 bnh_b(1024)
//   4352     bn2s(1024) 5376 bn2b(1024)
//   6400     wtb  [256][2304] bf16 (1,179,648)
//   1186048  w2b  [256][384]  bf16 (196,608)
//   1382656  wqp  [8][32][288] bf16 (147,456)
//   1536000  x_nhwc [102400][256] bf16 (52,428,800)
//   119500800 Ycat [102400][384] bf16 (78,643,200) -> total 198,144,000 B
// ---------------------------------------------------------------------------
extern "C" void kernel_launch(void* const* d_in, const int* in_sizes, int n_in,
                              void* d_out, int out_size, void* d_ws, size_t ws_size,
                              hipStream_t stream) {
  (void)in_sizes; (void)n_in; (void)out_size; (void)ws_size;
  const float* x    = (const float*)d_in[0];
  const float* qkvw = (const float*)d_in[1];
  const float* qg   = (const float*)d_in[2];
  const float* qb   = (const float*)d_in[3];
  const float* qm   = (const float*)d_in[4];
  const float* qv   = (const float*)d_in[5];
  const float* hw_  = (const float*)d_in[6];
  const float* hg   = (const float*)d_in[7];
  const float* hb   = (const float*)d_in[8];
  const float* hm   = (const float*)d_in[9];
  const float* hv   = (const float*)d_in[10];
  const float* ow   = (const float*)d_in[11];
  const float* og   = (const float*)d_in[12];
  const float* ob   = (const float*)d_in[13];
  const float* om   = (const float*)d_in[14];
  const float* ov   = (const float*)d_in[15];

  char* ws = (char*)d_ws;
  float* zpg   = (float*)(ws + 0);
  float* bnq_s = (float*)(ws + 256);
  float* bnq_b = (float*)(ws + 1280);
  float* bnh_s = (float*)(ws + 2304);
  float* bnh_b = (float*)(ws + 3328);
  float* bn2s  = (float*)(ws + 4352);
  float* bn2b  = (float*)(ws + 5376);
  u16*   wtb   = (u16*)(ws + 6400);
  u16*   w2b   = (u16*)(ws + 1186048);
  u16*   wqp   = (u16*)(ws + 1382656);
  u16*   xn    = (u16*)(ws + 1536000);
  u16*   ycat  = (u16*)(ws + 119500800);
  float* out   = (float*)d_out;

  prep_nchw<<<dim3(4, 80, 16), dim3(256), 0, stream>>>(
      x, qkvw, qg, qb, qm, qv, hw_, hg, hb, hm, hv, ow, og, ob, om, ov,
      xn, wtb, w2b, wqp, bnq_s, bnq_b, bnh_s, bnh_b, bn2s, bn2b, zpg);
  gemm_main<<<dim3(800), dim3(512), 0, stream>>>(
      xn, wtb, bnh_s, bnh_b, zpg, ycat);
  qkv_attn<<<dim3(800), dim3(512), 0, stream>>>(
      xn, wqp, bnq_s, bnq_b, ycat);
  gemm_out<<<dim3(2, 800), dim3(256), 0, stream>>>(
      w2b, ycat, bn2s, bn2b, out);
}

// Round 19
// 299.039 us; speedup vs baseline: 1.0977x; 1.0977x over previous
//
#include <hip/hip_runtime.h>
#include <stdint.h>

typedef unsigned short u16;
typedef unsigned int u32;
typedef __attribute__((ext_vector_type(4))) float f32x4;
typedef __attribute__((ext_vector_type(8))) __bf16 bf16x8;

#define EPS_BN 1e-5f

__device__ __forceinline__ u16 f2bf(float f) {
  u32 u = __builtin_bit_cast(u32, f);
  u32 r = (u + 0x7fffu + ((u >> 16) & 1u)) >> 16;
  return (u16)r;
}

__device__ __forceinline__ float silu_f(float v) {
  return v / (1.0f + __expf(-v));
}

// async global->LDS, 16B per lane; dest = wave-uniform base + lane*16
__device__ __forceinline__ void gll16(const void* g, void* l) {
  __builtin_amdgcn_global_load_lds(
      (__attribute__((address_space(1))) void*)(void*)g,
      (__attribute__((address_space(3))) void*)l, 16, 0, 0);
}

// ---------------------------------------------------------------------------
// FUSED prep + NCHW->NHWC transpose (r17-proven). 5120 blocks; every block
// does one (b,h,ctile) transpose tile; the first 2304 blocks also run prep's
// weight-pack/BN-fold lines (disjoint outputs -> race-free).
// ---------------------------------------------------------------------------
__global__ __launch_bounds__(256) void prep_nchw(
    const float* __restrict__ x,
    const float* __restrict__ qkv_w, const float* __restrict__ qg,
    const float* __restrict__ qb, const float* __restrict__ qm,
    const float* __restrict__ qv,
    const float* __restrict__ hid_w, const float* __restrict__ hg,
    const float* __restrict__ hb, const float* __restrict__ hm,
    const float* __restrict__ hv,
    const float* __restrict__ out_w, const float* __restrict__ og,
    const float* __restrict__ ob, const float* __restrict__ om,
    const float* __restrict__ ov,
    u16* __restrict__ xn,
    u16* __restrict__ wtb, u16* __restrict__ w2b, u16* __restrict__ wqp,
    float* __restrict__ bnq_s, float* __restrict__ bnq_b,
    float* __restrict__ bnh_s, float* __restrict__ bnh_b,
    float* __restrict__ bn2s, float* __restrict__ bn2b,
    float* __restrict__ zpg)
{
  __shared__ u16 T[80 * 66];
  const int t = threadIdx.x;
  const int ct = blockIdx.x;       // 0..3
  const int h  = blockIdx.y;       // 0..79
  const int b  = blockIdx.z;       // 0..15
  const int bid = blockIdx.x + blockIdx.y * 4 + blockIdx.z * 320;  // 0..5119
  const int gid = bid * 256 + t;

  // ---- prep lines (first 2304 blocks only) ----
  if (gid < 256 * 2304) {            // hid weights, channel-major
    int j = gid / 2304, k = gid - j * 2304;
    int tap = k >> 8, c = k & 255;
    wtb[gid] = f2bf(hid_w[(j * 256 + c) * 9 + tap]);
  }
  if (gid < 73728) {                 // qkv grouped weights [g][j<32][288]
    int g = gid / 9216;
    int r = gid - g * 9216;
    int j = r / 288, k = r - j * 288;
    int tap = k >> 5, cg = k & 31;
    float v = 0.f;
    if (j < 20) v = qkv_w[((g * 20 + j) * 32 + cg) * 9 + tap];
    wqp[gid] = f2bf(v);
  }
  if (gid < 98304) w2b[gid] = f2bf(out_w[gid]);   // [256][384]
  if (gid < 160) {
    float iv = qg[gid] * rsqrtf(qv[gid] + EPS_BN);
    bnq_s[gid] = iv; bnq_b[gid] = qb[gid] - qm[gid] * iv;
  }
  if (gid < 256) {
    float iv = hg[gid] * rsqrtf(hv[gid] + EPS_BN);
    bnh_s[gid] = iv; bnh_b[gid] = hb[gid] - hm[gid] * iv;
    float iv2 = og[gid] * rsqrtf(ov[gid] + EPS_BN);
    bn2s[gid] = iv2; bn2b[gid] = ob[gid] - om[gid] * iv2;
  }
  if (gid < 64) zpg[gid] = 0.f;

  // ---- transpose tile (all blocks) ----
  const float* src = x + ((size_t)b * 256 + ct * 64) * 6400 + h * 80;
  for (int it = 0; it < 5; ++it) {
    int idx = it * 256 + t;        // 0..1279 float4s
    int cl = idx / 20, w4 = idx - cl * 20;
    float4 v = *(const float4*)(src + (size_t)cl * 6400 + w4 * 4);
    T[(w4 * 4 + 0) * 66 + cl] = f2bf(v.x);
    T[(w4 * 4 + 1) * 66 + cl] = f2bf(v.y);
    T[(w4 * 4 + 2) * 66 + cl] = f2bf(v.z);
    T[(w4 * 4 + 3) * 66 + cl] = f2bf(v.w);
  }
  __syncthreads();
  u16* dst = xn + ((size_t)(b * 80 + h) * 80) * 256 + ct * 64;
  for (int it = 0; it < 5; ++it) {
    int idx = it * 256 + t;
    int wl = idx >> 4;
    int cl = (idx & 15) * 4;
    ushort4 v4;
    v4.x = T[wl * 66 + cl + 0];
    v4.y = T[wl * 66 + cl + 1];
    v4.z = T[wl * 66 + cl + 2];
    v4.w = T[wl * 66 + cl + 3];
    *(ushort4*)(dst + (size_t)wl * 256 + cl) = v4;
  }
}

// ---------------------------------------------------------------------------
// hid GEMM (r13-proven, 146us): 128px x 256ch per block, 8 waves
// (wave = 64px x 64col strip), 2-barrier K-step, XOR swizzle, A staged once
// per step in the 36-step interleaved order (cross-block L2 locality).
// ---------------------------------------------------------------------------
__global__ __launch_bounds__(512, 4) void gemm_main(
    const u16* __restrict__ xn, const u16* __restrict__ wt,
    const float* __restrict__ bns, const float* __restrict__ bnb,
    const float* __restrict__ zpg, u16* __restrict__ ycat)
{
  __shared__ __attribute__((aligned(16))) u16 Al[128 * 64];  // 16 KB
  __shared__ __attribute__((aligned(16))) u16 Bl[256 * 64];  // 32 KB
  const int t = threadIdx.x;
  const int wave = t >> 6, lane = t & 63;
  const int wm = wave >> 2;            // 0..1 : 64-px strip
  const int wn = wave & 3;             // 0..3 : 64-col strip
  // bijective XCD swizzle: nwg = 800 = 8*100
  const int orig = blockIdx.x;
  const int wg = (orig & 7) * 100 + (orig >> 3);
  const int ptile = wg * 128;

  const int srcc = (((lane & 7) ^ ((lane >> 3) & 7)) * 8);
  const int c16 = lane & 15, lq = lane >> 4;

  int pbA[2], hhA[2], wwA[2];
#pragma unroll
  for (int l = 0; l < 2; ++l) {
    int row = wave * 8 + (lane >> 3) + l * 64;
    int p = ptile + row;
    pbA[l] = p;
    int hw = p % 6400;
    hhA[l] = hw / 80;
    wwA[l] = hw - (hw / 80) * 80;
  }
  int bofB[4];
#pragma unroll
  for (int l = 0; l < 4; ++l) {
    int row = wave * 8 + (lane >> 3) + l * 64;
    bofB[l] = row * 2304 + srcc;
  }

  f32x4 acc[4][4];
#pragma unroll
  for (int m = 0; m < 4; ++m)
#pragma unroll
    for (int n = 0; n < 4; ++n) {
      f32x4 z = {0.f, 0.f, 0.f, 0.f};
      acc[m][n] = z;
    }

  for (int ks = 0; ks < 36; ++ks) {
    const int k0 = ks * 64;
    const int tap = ks >> 2;
    const int c0 = (ks & 3) * 64;
    const int dh = tap / 3 - 1, dw = tap - (tap / 3) * 3 - 1;
    const int dp = dh * 80 + dw;
    __syncthreads();
#pragma unroll
    for (int l = 0; l < 2; ++l) {
      bool ok = ((unsigned)(hhA[l] + dh) < 80u) & ((unsigned)(wwA[l] + dw) < 80u);
      const u16* src = ok
          ? (xn + ((size_t)(pbA[l] + dp) * 256 + c0 + srcc))
          : (const u16*)zpg;
      gll16(src, Al + (wave * 8 + l * 64) * 64);
    }
#pragma unroll
    for (int l = 0; l < 4; ++l)
      gll16(wt + (size_t)(bofB[l] + k0), Bl + (wave * 8 + l * 64) * 64);
    __syncthreads();
#pragma unroll
    for (int kk = 0; kk < 2; ++kk) {
      const int q = kk * 4 + lq;
      bf16x8 av[4], bv[4];
#pragma unroll
      for (int m = 0; m < 4; ++m) {
        int r = wm * 64 + m * 16 + c16;           // 0..127
        av[m] = *(const bf16x8*)(Al + r * 64 + (q ^ (r & 7)) * 8);
      }
#pragma unroll
      for (int n = 0; n < 4; ++n) {
        int j = wn * 64 + n * 16 + c16;           // 0..255
        bv[n] = *(const bf16x8*)(Bl + j * 64 + (q ^ (j & 7)) * 8);
      }
#pragma unroll
      for (int m = 0; m < 4; ++m)
#pragma unroll
        for (int n = 0; n < 4; ++n)
          acc[m][n] = __builtin_amdgcn_mfma_f32_16x16x32_bf16(
              av[m], bv[n], acc[m][n], 0, 0, 0);
    }
  }

  const int rg = lq;
#pragma unroll
  for (int n = 0; n < 4; ++n) {
    int j = wn * 64 + n * 16 + c16;               // 0..255
    float sc = bns[j], bi = bnb[j];
#pragma unroll
    for (int m = 0; m < 4; ++m) {
      int p0 = ptile + wm * 64 + m * 16 + rg * 4;
#pragma unroll
      for (int r = 0; r < 4; ++r) {
        float v = silu_f(acc[m][n][r] * sc + bi);
        ycat[(size_t)(p0 + r) * 384 + 128 + j] = f2bf(v);
      }
    }
  }
}

// ---------------------------------------------------------------------------
// FUSED qkv grouped conv + per-pixel attention, HALO-STAGED (r12-proven,
// ~55us): per 64-ch chunk cc, stage pixel window [ptile-88, ptile+232) once
// ([320][64] bf16 = 40KB, DOUBLE-buffered: STAGE(cc+1) issued before the
// 9-tap compute so HBM latency hides under MFMA). Conv zero-pad via per-lane
// cndmask. Epilogue: qs[128][160] fp32 overlay -> softmax + PV -> Ycat 0..127.
// ---------------------------------------------------------------------------
__global__ __launch_bounds__(256, 2) void qkv_attn(
    const u16* __restrict__ xn, const u16* __restrict__ wqp,
    const float* __restrict__ bnq_s, const float* __restrict__ bnq_b,
    u16* __restrict__ ycat)
{
  __shared__ __attribute__((aligned(16))) char LB[81920];
  u16* HB0 = (u16*)LB;                 // halo buf 0: [320*64]
  u16* HB1 = (u16*)(LB + 40960);       // halo buf 1
  float* qs = (float*)LB;              // overlay: [128][160] fp32

  const int t = threadIdx.x;
  const int wave = t >> 6, lane = t & 63;
  // bijective XCD swizzle: nwg = 800 = 8*100
  const int orig = blockIdx.x;
  const int wg = (orig & 7) * 100 + (orig >> 3);
  const int ptile = wg * 128;
  const int pbase = ptile - 88;        // multiple of 8 -> swizzle rows align

  const int srcc = (((lane & 7) ^ ((lane >> 3) & 7)) * 8);
  const int q = lane >> 4, c16 = lane & 15;

  // per-lane pixel coords for its two fragment rows (m=0,1)
  int ph[2], pw[2];
#pragma unroll
  for (int m = 0; m < 2; ++m) {
    int p = ptile + wave * 32 + m * 16 + c16;
    int hw = p % 6400;
    ph[m] = hw / 80;
    pw[m] = hw - (hw / 80) * 80;
  }

  // stage halo window for channel chunk cc into dst (10 gll16 per wave)
  auto STAGE_H = [&](int cc, u16* dst) {
#pragma unroll
    for (int r = 0; r < 10; ++r) {
      int row = r * 32 + wave * 8 + (lane >> 3);
      int p = pbase + row;
      int pc = p < 0 ? 0 : (p > 102399 ? 102399 : p);
      gll16(xn + (size_t)pc * 256 + cc * 64 + srcc,
            dst + (r * 32 + wave * 8) * 64);
    }
  };

  bf16x8 zv;
#pragma unroll
  for (int i = 0; i < 8; ++i) zv[i] = (__bf16)0.0f;

  f32x4 acc[2][16];
#pragma unroll
  for (int m = 0; m < 2; ++m)
#pragma unroll
    for (int f = 0; f < 16; ++f) {
      f32x4 z = {0.f, 0.f, 0.f, 0.f};
      acc[m][f] = z;
    }

  STAGE_H(0, HB0);
  asm volatile("s_waitcnt vmcnt(0)" ::: "memory");
  __builtin_amdgcn_sched_barrier(0);
  __syncthreads();

#pragma unroll
  for (int cc = 0; cc < 4; ++cc) {
    const u16* HBc = (cc & 1) ? HB1 : HB0;
    u16* HBn = (cc & 1) ? HB0 : HB1;
    if (cc < 3) STAGE_H(cc + 1, HBn);   // in flight across the whole compute
    for (int tap = 0; tap < 9; ++tap) {
      const int dh = tap / 3 - 1, dw = tap - (tap / 3) * 3 - 1;
      const int dp = dh * 80 + dw;
      bf16x8 bq[2][2];
#pragma unroll
      for (int h = 0; h < 2; ++h)
#pragma unroll
        for (int nf = 0; nf < 2; ++nf) {
          int row = (2 * cc + h) * 32 + nf * 16 + c16;
          bq[h][nf] =
              *(const bf16x8*)(wqp + (size_t)row * 288 + tap * 32 + q * 8);
        }
      bf16x8 av[2][2];
#pragma unroll
      for (int m = 0; m < 2; ++m) {
        int rl = wave * 32 + m * 16 + c16 + 88 + dp;   // halo row
        bool ok = ((unsigned)(ph[m] + dh) < 80u) &
                  ((unsigned)(pw[m] + dw) < 80u);
#pragma unroll
        for (int h = 0; h < 2; ++h) {
          int q8 = h * 4 + q;
          bf16x8 raw = *(const bf16x8*)(HBc + rl * 64 + ((q8 ^ (rl & 7)) * 8));
          av[m][h] = ok ? raw : zv;
        }
      }
#pragma unroll
      for (int h = 0; h < 2; ++h)
#pragma unroll
        for (int m = 0; m < 2; ++m)
#pragma unroll
          for (int nf = 0; nf < 2; ++nf)
            acc[m][(2 * cc + h) * 2 + nf] = __builtin_amdgcn_mfma_f32_16x16x32_bf16(
                av[m][h], bq[h][nf], acc[m][(2 * cc + h) * 2 + nf], 0, 0, 0);
    }
    if (cc < 3) {
      asm volatile("s_waitcnt vmcnt(0)" ::: "memory");  // pre-drained by compute
      __builtin_amdgcn_sched_barrier(0);
      __syncthreads();
    }
  }

  // fence all waves before the qs overlay is written over the halo buffers
  asm volatile("s_waitcnt vmcnt(0)" ::: "memory");
  __builtin_amdgcn_sched_barrier(0);
  __syncthreads();

  // epilogue: BN+SiLU -> qs[pixel][oc] fp32 (pixel 0..127, oc 0..159)
#pragma unroll
  for (int f = 0; f < 16; ++f) {
    int jj = (f & 1) * 16 + c16;
    if (jj >= 20) continue;
    int oc = (f >> 1) * 20 + jj;
    float sc = bnq_s[oc], bi = bnq_b[oc];
#pragma unroll
    for (int m = 0; m < 2; ++m) {
      int pl0 = wave * 32 + m * 16 + q * 4;
#pragma unroll
      for (int r = 0; r < 4; ++r)
        qs[(pl0 + r) * 160 + oc] = silu_f(acc[m][f][r] * sc + bi);
    }
  }
  __syncthreads();

  // attention: thread -> (px, i); 8 iters cover 128 px * 16 i.
  for (int it = 0; it < 8; ++it) {
    int idx = it * 256 + t;
    int px = idx >> 4, i = idx & 15;
    const float* row = qs + px * 160;
    const float qi = row[i];
    float s[16];
    float mx = -3.4e38f;
#pragma unroll
    for (int j = 0; j < 16; ++j) { s[j] = qi * row[16 + j]; mx = fmaxf(mx, s[j]); }
    float sum = 0.f;
#pragma unroll
    for (int j = 0; j < 16; ++j) { s[j] = __expf(s[j] - mx); sum += s[j]; }
    const float inv = 1.0f / sum;
    float y[8];
#pragma unroll
    for (int d = 0; d < 8; ++d) y[d] = 0.f;
#pragma unroll
    for (int j = 0; j < 16; ++j) {
      const float a = s[j];
      const float* vr = row + 32 + j * 8;
#pragma unroll
      for (int d = 0; d < 8; ++d) y[d] += a * vr[d];
    }
    union { u16 u[8]; uint4 v4; } pk;
#pragma unroll
    for (int d = 0; d < 8; ++d) pk.u[d] = f2bf(y[d] * inv);
    *(uint4*)(ycat + (size_t)(ptile + px) * 384 + i * 8) = pk.v4;
  }
}

// ---------------------------------------------------------------------------
// Output GEMM (r12-proven form, ~45us = near its HBM/L3 roofline):
// 128oc x 128px per block, 256 threads, 2-barrier K-step, XOR swizzle,
// XCD swizzle over 1600 wgs. Coalesced NCHW fp32 stores.
// ---------------------------------------------------------------------------
__global__ __launch_bounds__(256, 2) void gemm_out(
    const u16* __restrict__ w2, const u16* __restrict__ ycat,
    const float* __restrict__ bns, const float* __restrict__ bnb,
    float* __restrict__ out)
{
  __shared__ __attribute__((aligned(16))) u16 Al[128 * 64];
  __shared__ __attribute__((aligned(16))) u16 Bl[128 * 64];
  const int t = threadIdx.x;
  const int wave = t >> 6, lane = t & 63;
  const int wr = wave >> 1, wc = wave & 1;
  const int orig = blockIdx.y * 2 + blockIdx.x;
  const int wg = (orig & 7) * 200 + (orig >> 3);
  const int octile = (wg / 800) * 128;
  const int ptile = (wg % 800) * 128;

  const int srcc = (((lane & 7) ^ ((lane >> 3) & 7)) * 8);
  int bofA[4], bofB[4];
#pragma unroll
  for (int c = 0; c < 4; ++c) {
    int m = wave * 32 + c * 8 + (lane >> 3);
    bofA[c] = (octile + m) * 384 + srcc;
    bofB[c] = (ptile + m) * 384 + srcc;
  }
  u16* AlW = Al + wave * 2048;
  u16* BlW = Bl + wave * 2048;

  f32x4 acc[4][4];
#pragma unroll
  for (int m = 0; m < 4; ++m)
#pragma unroll
    for (int n = 0; n < 4; ++n) {
      f32x4 z = {0.f, 0.f, 0.f, 0.f};
      acc[m][n] = z;
    }

  for (int ks = 0; ks < 6; ++ks) {
    const int k0 = ks * 64;
    __syncthreads();
#pragma unroll
    for (int c = 0; c < 4; ++c) gll16(w2 + (size_t)(bofA[c] + k0), AlW + c * 512);
#pragma unroll
    for (int c = 0; c < 4; ++c) gll16(ycat + (size_t)(bofB[c] + k0), BlW + c * 512);
    __syncthreads();
#pragma unroll
    for (int kk = 0; kk < 2; ++kk) {
      const int q = kk * 4 + (lane >> 4);
      const int c16 = lane & 15;
      bf16x8 av[4], bv[4];
#pragma unroll
      for (int m = 0; m < 4; ++m) {
        int r = wr * 64 + m * 16 + c16;
        av[m] = *(const bf16x8*)(Al + r * 64 + (q ^ (r & 7)) * 8);
      }
#pragma unroll
      for (int n = 0; n < 4; ++n) {
        int r = wc * 64 + n * 16 + c16;
        bv[n] = *(const bf16x8*)(Bl + r * 64 + (q ^ (r & 7)) * 8);
      }
#pragma unroll
      for (int m = 0; m < 4; ++m)
#pragma unroll
        for (int n = 0; n < 4; ++n)
          acc[m][n] = __builtin_amdgcn_mfma_f32_16x16x32_bf16(
              av[m], bv[n], acc[m][n], 0, 0, 0);
    }
  }

  const int c16 = lane & 15, rg = lane >> 4;
  const int b = ptile / 6400;
  const int hwb = ptile - b * 6400;
#pragma unroll
  for (int m = 0; m < 4; ++m) {
    int oc0 = octile + wr * 64 + m * 16 + rg * 4;
#pragma unroll
    for (int n = 0; n < 4; ++n) {
      int hw = hwb + wc * 64 + n * 16 + c16;
#pragma unroll
      for (int r = 0; r < 4; ++r) {
        int oc = oc0 + r;
        float v = silu_f(acc[m][n][r] * bns[oc] + bnb[oc]);
        out[((size_t)b * 256 + oc) * 6400 + hw] = v;
      }
    }
  }
}

// ---------------------------------------------------------------------------
// ws layout (bytes):
//   0        zero page (256)
//   256      bnq_s(640) 1280 bnq_b(640) 2304 bnh_s(1024) 3328 bnh_b(1024)
//   4352     bn2s(1024) 5376 bn2b(1024)
//   6400     wtb  [256][2304] bf16 (1,179,648)
//   1186048  w2b  [256][384]  bf16 (196,608)
//   1382656  wqp  [8][32][288] bf16 (147,456)
//   1536000  x_nhwc [102400][256] bf16 (52,428,800)
//   119500800 Ycat [102400][384] bf16 (78,643,200) -> total 198,144,000 B
// ---------------------------------------------------------------------------
extern "C" void kernel_launch(void* const* d_in, const int* in_sizes, int n_in,
                              void* d_out, int out_size, void* d_ws, size_t ws_size,
                              hipStream_t stream) {
  (void)in_sizes; (void)n_in; (void)out_size; (void)ws_size;
  const float* x    = (const float*)d_in[0];
  const float* qkvw = (const float*)d_in[1];
  const float* qg   = (const float*)d_in[2];
  const float* qb   = (const float*)d_in[3];
  const float* qm   = (const float*)d_in[4];
  const float* qv   = (const float*)d_in[5];
  const float* hw_  = (const float*)d_in[6];
  const float* hg   = (const float*)d_in[7];
  const float* hb   = (const float*)d_in[8];
  const float* hm   = (const float*)d_in[9];
  const float* hv   = (const float*)d_in[10];
  const float* ow   = (const float*)d_in[11];
  const float* og   = (const float*)d_in[12];
  const float* ob   = (const float*)d_in[13];
  const float* om   = (const float*)d_in[14];
  const float* ov   = (const float*)d_in[15];

  char* ws = (char*)d_ws;
  float* zpg   = (float*)(ws + 0);
  float* bnq_s = (float*)(ws + 256);
  float* bnq_b = (float*)(ws + 1280);
  float* bnh_s = (float*)(ws + 2304);
  float* bnh_b = (float*)(ws + 3328);
  float* bn2s  = (float*)(ws + 4352);
  float* bn2b  = (float*)(ws + 5376);
  u16*   wtb   = (u16*)(ws + 6400);
  u16*   w2b   = (u16*)(ws + 1186048);
  u16*   wqp   = (u16*)(ws + 1382656);
  u16*   xn    = (u16*)(ws + 1536000);
  u16*   ycat  = (u16*)(ws + 119500800);
  float* out   = (float*)d_out;

  prep_nchw<<<dim3(4, 80, 16), dim3(256), 0, stream>>>(
      x, qkvw, qg, qb, qm, qv, hw_, hg, hb, hm, hv, ow, og, ob, om, ov,
      xn, wtb, w2b, wqp, bnq_s, bnq_b, bnh_s, bnh_b, bn2s, bn2b, zpg);
  gemm_main<<<dim3(800), dim3(512), 0, stream>>>(
      xn, wtb, bnh_s, bnh_b, zpg, ycat);
  qkv_attn<<<dim3(800), dim3(256), 0, stream>>>(
      xn, wqp, bnq_s, bnq_b, ycat);
  gemm_out<<<dim3(2, 800), dim3(256), 0, stream>>>(
      w2b, ycat, bn2s, bn2b, out);
}